// Round 1
// baseline (179.872 us; speedup 1.0000x reference)
//
#include <hip/hip_runtime.h>

#define RADIUS 5
#define WIN 9
#define BB 4
#define KK 4
#define HH 224
#define WW 224
#define HW (HH * WW)

// partial layout in d_ws: [b][8] floats; idx 0..3 = A_k, 4..7 = V_k
__global__ __launch_bounds__(256) void ncuts_main(
    const float* __restrict__ seg,     // [B,K,H,W]
    const float* __restrict__ weight,  // [B,1,H,W,9,9]
    float* __restrict__ partial)       // 32 floats, pre-zeroed
{
    const int tid = blockIdx.x * blockDim.x + threadIdx.x;  // pixel id, exact
    const int b   = tid / HW;
    const int rem = tid - b * HW;
    const int h   = rem / WW;
    const int w   = rem - h * WW;

    const float* wp   = weight + (size_t)tid * (WIN * WIN);
    const float* segb = seg + (size_t)b * KK * HW;

    float accA0 = 0.f, accA1 = 0.f, accA2 = 0.f, accA3 = 0.f, wsum = 0.f;

    #pragma unroll
    for (int m = 0; m < WIN; ++m) {
        const int hh = h + m - RADIUS;
        const bool okh = (hh >= 0) & (hh < HH);
        #pragma unroll
        for (int n = 0; n < WIN; ++n) {
            const float wv = wp[m * WIN + n];
            wsum += wv;
            const int ww = w + n - RADIUS;
            const bool ok = okh & (ww >= 0) & (ww < WW);
            const int base = hh * WW + ww;
            const float s0 = ok ? segb[0 * HW + base] : 0.f;
            const float s1 = ok ? segb[1 * HW + base] : 0.f;
            const float s2 = ok ? segb[2 * HW + base] : 0.f;
            const float s3 = ok ? segb[3 * HW + base] : 0.f;
            accA0 += wv * s0;
            accA1 += wv * s1;
            accA2 += wv * s2;
            accA3 += wv * s3;
        }
    }

    const int own = h * WW + w;
    const float t0 = segb[0 * HW + own];
    const float t1 = segb[1 * HW + own];
    const float t2 = segb[2 * HW + own];
    const float t3 = segb[3 * HW + own];

    float vals[8] = { accA0 * t0, accA1 * t1, accA2 * t2, accA3 * t3,
                      wsum * t0,  wsum * t1,  wsum * t2,  wsum * t3 };

    __shared__ float red[4][8];
    const int lane = threadIdx.x & 63;
    const int wid  = threadIdx.x >> 6;

    #pragma unroll
    for (int i = 0; i < 8; ++i) {
        float v = vals[i];
        v += __shfl_down(v, 32);
        v += __shfl_down(v, 16);
        v += __shfl_down(v, 8);
        v += __shfl_down(v, 4);
        v += __shfl_down(v, 2);
        v += __shfl_down(v, 1);
        if (lane == 0) red[wid][i] = v;
    }
    __syncthreads();

    if (threadIdx.x < 8) {
        const float s = red[0][threadIdx.x] + red[1][threadIdx.x] +
                        red[2][threadIdx.x] + red[3][threadIdx.x];
        atomicAdd(&partial[b * 8 + threadIdx.x], s);
    }
}

__global__ void ncuts_final(const float* __restrict__ partial,
                            float* __restrict__ out)
{
    if (threadIdx.x == 0 && blockIdx.x == 0) {
        float total = 0.f;
        for (int b = 0; b < BB; ++b) {
            float assoc = 0.f;
            for (int k = 0; k < KK; ++k) {
                const float A = partial[b * 8 + k];
                const float V = partial[b * 8 + 4 + k];
                assoc += A / V;
            }
            total += (float)KK - assoc;
        }
        out[0] = total;
    }
}

extern "C" void kernel_launch(void* const* d_in, const int* in_sizes, int n_in,
                              void* d_out, int out_size, void* d_ws, size_t ws_size,
                              hipStream_t stream) {
    const float* seg    = (const float*)d_in[0];
    const float* weight = (const float*)d_in[1];
    float* out     = (float*)d_out;
    float* partial = (float*)d_ws;

    hipMemsetAsync(d_ws, 0, 32 * sizeof(float), stream);

    const int total_px = BB * HW;           // 200704
    const int block = 256;
    const int grid  = total_px / block;     // 784, exact

    hipLaunchKernelGGL(ncuts_main, dim3(grid), dim3(block), 0, stream,
                       seg, weight, partial);
    hipLaunchKernelGGL(ncuts_final, dim3(1), dim3(64), 0, stream, partial, out);
}

// Round 2
// 106.712 us; speedup vs baseline: 1.6856x; 1.6856x over previous
//
#include <hip/hip_runtime.h>

#define RADIUS 5
#define WIN 9
#define BB 4
#define KK 4
#define HH 224
#define WW 224
#define HW (HH * WW)
#define PD 234                 // HH + 2*RADIUS  (padded dim)
#define PAREA (PD * PD)        // 54756
#define NBUCKET 64
#define PARTIAL_FLOATS (NBUCKET * BB * 8)   // 2048 floats = 8 KB
#define BLOCKS_PER_B (HW / 64)              // 784

// d_ws layout (floats):
//   [0, 2048)                      : partial buckets [bucket][b][8] (0..3 A_k, 4..7 V_k)
//   [2048, 2048 + B*PAREA*4)       : padded seg P[b][r][c][k], float4 per (r,c)

// ---------- pre-pass: seg [B,K,H,W] -> zero-padded [B,PD,PD,K] (float4) ----------
__global__ __launch_bounds__(256) void ncuts_pad(
    const float* __restrict__ seg, float4* __restrict__ pseg)
{
    const int tid = blockIdx.x * 256 + threadIdx.x;
    if (tid >= BB * PAREA) return;
    const int b  = tid / PAREA;
    const int rc = tid - b * PAREA;
    const int r  = rc / PD;
    const int c  = rc - r * PD;
    const int hh = r - RADIUS;
    const int ww = c - RADIUS;
    float4 v = {0.f, 0.f, 0.f, 0.f};
    if (hh >= 0 && hh < HH && ww >= 0 && ww < WW) {
        const float* sb = seg + (size_t)b * KK * HW + hh * WW + ww;
        v.x = sb[0 * HW];
        v.y = sb[1 * HW];
        v.z = sb[2 * HW];
        v.w = sb[3 * HW];
    }
    pseg[tid] = v;
}

// ---------- main: one wave = 64 consecutive pixels ----------
__global__ __launch_bounds__(64) void ncuts_main(
    const float* __restrict__ weight,
    const float4* __restrict__ pseg,
    float* __restrict__ partial)
{
    __shared__ float wlds[64 * 81];   // 20736 B

    const int lane = threadIdx.x;     // 0..63
    const int tid  = blockIdx.x * 64 + lane;   // pixel id
    const int b    = tid / HW;        // uniform per block (784 blocks per b)
    const int rem  = tid - b * HW;
    const int h    = rem / WW;
    const int w    = rem - h * WW;

    // --- stage this wave's 64*81 weights into LDS, fully coalesced ---
    // base byte offset = blockIdx.x * 64*81*4 = blockIdx.x * 20736 (16B aligned)
    const float4* wsrc = (const float4*)(weight + (size_t)blockIdx.x * (64 * 81));
    float4* wdst = (float4*)wlds;
    #pragma unroll
    for (int j = 0; j < 20; ++j)
        wdst[j * 64 + lane] = wsrc[j * 64 + lane];
    if (lane < 16)
        wdst[1280 + lane] = wsrc[1280 + lane];
    __syncthreads();

    const float4* p4 = pseg + (size_t)b * PAREA;
    const float* wl  = &wlds[lane * 81];

    float a0 = 0.f, a1 = 0.f, a2 = 0.f, a3 = 0.f, wsum = 0.f;

    #pragma unroll
    for (int m = 0; m < WIN; ++m) {
        const int base = (h + m) * PD + w;
        #pragma unroll
        for (int n = 0; n < WIN; ++n) {
            const float wv = wl[m * WIN + n];
            const float4 s = p4[base + n];
            a0 = fmaf(wv, s.x, a0);
            a1 = fmaf(wv, s.y, a1);
            a2 = fmaf(wv, s.z, a2);
            a3 = fmaf(wv, s.w, a3);
            wsum += wv;
        }
    }

    const float4 t = p4[(h + RADIUS) * PD + (w + RADIUS)];

    float vals[8] = { a0 * t.x, a1 * t.y, a2 * t.z, a3 * t.w,
                      wsum * t.x, wsum * t.y, wsum * t.z, wsum * t.w };

    #pragma unroll
    for (int i = 0; i < 8; ++i) {
        float v = vals[i];
        v += __shfl_down(v, 32);
        v += __shfl_down(v, 16);
        v += __shfl_down(v, 8);
        v += __shfl_down(v, 4);
        v += __shfl_down(v, 2);
        v += __shfl_down(v, 1);
        vals[i] = v;
    }

    if (lane == 0) {
        const int bb     = blockIdx.x - b * BLOCKS_PER_B;
        const int bucket = bb & (NBUCKET - 1);
        float* dst = partial + (bucket * BB + b) * 8;
        #pragma unroll
        for (int i = 0; i < 8; ++i)
            atomicAdd(dst + i, vals[i]);
    }
}

// ---------- final: fold buckets, compute loss ----------
__global__ __launch_bounds__(64) void ncuts_final(
    const float* __restrict__ partial, float* __restrict__ out)
{
    __shared__ float sums[32];
    const int t = threadIdx.x;
    if (t < 32) {
        // t -> (b = t>>3, i = t&7)
        const int b = t >> 3;
        const int i = t & 7;
        float s = 0.f;
        for (int bucket = 0; bucket < NBUCKET; ++bucket)
            s += partial[(bucket * BB + b) * 8 + i];
        sums[b * 8 + i] = s;
    }
    __syncthreads();
    if (t == 0) {
        float total = 0.f;
        for (int b = 0; b < BB; ++b) {
            float assoc = 0.f;
            for (int k = 0; k < KK; ++k) {
                const float A = sums[b * 8 + k];
                const float V = sums[b * 8 + 4 + k];
                assoc += A / V;
            }
            total += (float)KK - assoc;
        }
        out[0] = total;
    }
}

extern "C" void kernel_launch(void* const* d_in, const int* in_sizes, int n_in,
                              void* d_out, int out_size, void* d_ws, size_t ws_size,
                              hipStream_t stream) {
    const float* seg    = (const float*)d_in[0];
    const float* weight = (const float*)d_in[1];
    float* out     = (float*)d_out;
    float* wsf     = (float*)d_ws;
    float* partial = wsf;                       // 2048 floats
    float4* pseg   = (float4*)(wsf + PARTIAL_FLOATS);  // byte offset 8192, 16B aligned

    // zero the partial buckets only (8 KB)
    hipMemsetAsync(d_ws, 0, PARTIAL_FLOATS * sizeof(float), stream);

    // pre-pass: padded seg
    {
        const int total = BB * PAREA;           // 219024
        const int grid  = (total + 255) / 256;  // 856
        hipLaunchKernelGGL(ncuts_pad, dim3(grid), dim3(256), 0, stream, seg, pseg);
    }

    // main
    {
        const int grid = BB * BLOCKS_PER_B;     // 3136 blocks of 64
        hipLaunchKernelGGL(ncuts_main, dim3(grid), dim3(64), 0, stream,
                           weight, pseg, partial);
    }

    hipLaunchKernelGGL(ncuts_final, dim3(1), dim3(64), 0, stream, partial, out);
}